// Round 2
// baseline (343.328 us; speedup 1.0000x reference)
//
#include <hip/hip_runtime.h>

#define NN 2048
#define EE 65536
#define HIDD 12
#define NH 4
#define TEDD 16
#define NCLSS 4
#define H48 48

// monotonic unsigned encoding of float for atomicMax
__device__ __forceinline__ unsigned fkey(float f){
  unsigned u = __float_as_uint(f);
  return (u & 0x80000000u) ? ~u : (u | 0x80000000u);
}
__device__ __forceinline__ float fdec(unsigned kk){
  unsigned u = (kk & 0x80000000u) ? (kk & 0x7FFFFFFFu) : ~kk;
  return __uint_as_float(u);
}

__device__ __forceinline__ float read_t(const int* p){
  int i = *p;
  if (i >= 0 && i < 100000) return (float)i;   // int-encoded scalar (expected)
  return __int_as_float(i);                     // defensive: float-encoded scalar
}

// ---- time embedding: te[16] = sin_embed(t/100) @ time_W + time_b ----
__global__ void k_te(const int* __restrict__ t, const float* __restrict__ W,
                     const float* __restrict__ b, float* __restrict__ te)
{
  __shared__ float emb[TEDD];
  int tid = threadIdx.x;
  float tf = read_t(t) / 100.0f;
  if (tid < 8){
    float scale = __logf(10000.0f) / 7.0f;
    float v = tf * __expf(-(float)tid * scale);
    emb[tid]   = __sinf(v);
    emb[tid+8] = __cosf(v);
  }
  __syncthreads();
  if (tid < TEDD){
    float acc = b[tid];
    #pragma unroll
    for (int k=0;k<TEDD;k++) acc = fmaf(emb[k], W[k*TEDD+tid], acc);
    te[tid] = acc;
  }
}

// ---- zero init of softmax accumulators ----
__global__ void k_init(unsigned* __restrict__ mkey, float* __restrict__ s,
                       float* __restrict__ agg)
{
  int i = blockIdx.x*blockDim.x + threadIdx.x;
  if (i < NN*NH){ mkey[i] = 0u; s[i] = 0.f; }
  if (i < NN*NH*HIDD) agg[i] = 0.f;
}

// ---- layer-1 q,k,v,skip from [one-hot x | te] (20-dim input) ----
__global__ void k_qkv1(const float* __restrict__ x, const float* __restrict__ te,
    const float* __restrict__ Wq, const float* __restrict__ bq,
    const float* __restrict__ Wk, const float* __restrict__ bk,
    const float* __restrict__ Wv, const float* __restrict__ bv,
    const float* __restrict__ Ws, const float* __restrict__ bs,
    float* __restrict__ q, float* __restrict__ k, float* __restrict__ v,
    float* __restrict__ skip)
{
  int idx = blockIdx.x*blockDim.x + threadIdx.x;
  if (idx >= NN*H48) return;
  int node = idx / H48, j = idx - node*H48;
  float xin[20];
  #pragma unroll
  for (int c=0;c<NCLSS;c++) xin[c] = x[node*NCLSS+c];
  #pragma unroll
  for (int c=0;c<TEDD;c++) xin[NCLSS+c] = te[c];
  float aq=bq[j], ak=bk[j], av=bv[j];
  #pragma unroll
  for (int c=0;c<20;c++){
    float xc = xin[c];
    aq = fmaf(xc, Wq[c*H48+j], aq);
    ak = fmaf(xc, Wk[c*H48+j], ak);
    av = fmaf(xc, Wv[c*H48+j], av);
  }
  q[idx]=aq; k[idx]=ak; v[idx]=av;
  if (j < HIDD){
    float as = bs[j];
    #pragma unroll
    for (int c=0;c<20;c++) as = fmaf(xin[c], Ws[c*HIDD+j], as);
    skip[node*HIDD+j]=as;
  }
}

// ---- layer-2 q,k,v,skip from h (12-dim input) ----
__global__ void k_qkv2(const float* __restrict__ hin,
    const float* __restrict__ Wq, const float* __restrict__ bq,
    const float* __restrict__ Wk, const float* __restrict__ bk,
    const float* __restrict__ Wv, const float* __restrict__ bv,
    const float* __restrict__ Ws, const float* __restrict__ bs,
    float* __restrict__ q, float* __restrict__ k, float* __restrict__ v,
    float* __restrict__ skip)
{
  int idx = blockIdx.x*blockDim.x + threadIdx.x;
  if (idx >= NN*H48) return;
  int node = idx / H48, j = idx - node*H48;
  float xin[HIDD];
  #pragma unroll
  for (int c=0;c<HIDD;c++) xin[c] = hin[node*HIDD+c];
  float aq=bq[j], ak=bk[j], av=bv[j];
  #pragma unroll
  for (int c=0;c<HIDD;c++){
    float xc = xin[c];
    aq = fmaf(xc, Wq[c*H48+j], aq);
    ak = fmaf(xc, Wk[c*H48+j], ak);
    av = fmaf(xc, Wv[c*H48+j], av);
  }
  q[idx]=aq; k[idx]=ak; v[idx]=av;
  if (j < HIDD){
    float as = bs[j];
    #pragma unroll
    for (int c=0;c<HIDD;c++) as = fmaf(xin[c], Ws[c*HIDD+j], as);
    skip[node*HIDD+j]=as;
  }
}

// ---- per-edge-head attention score + running max over dst ----
__global__ void k_score(const int* __restrict__ ei, const float* __restrict__ q,
                        const float* __restrict__ k, float* __restrict__ score,
                        unsigned* __restrict__ mkey)
{
  int idx = blockIdx.x*blockDim.x + threadIdx.x;
  if (idx >= EE*NH) return;
  int e = idx >> 2, h = idx & 3;
  int src = ei[e], dst = ei[EE + e];
  const float* qp = q + dst*H48 + h*HIDD;
  const float* kp = k + src*H48 + h*HIDD;
  float acc = 0.f;
  #pragma unroll
  for (int d=0; d<HIDD; d++) acc = fmaf(qp[d], kp[d], acc);
  acc *= 0.28867513459481287f;   // 1/sqrt(12)
  score[idx] = acc;
  atomicMax(&mkey[dst*NH + h], fkey(acc));
}

// ---- exp weights + scatter-accumulate numerator and denominator ----
__global__ void k_agg(const int* __restrict__ ei, const float* __restrict__ score,
                      const unsigned* __restrict__ mkey, const float* __restrict__ v,
                      float* __restrict__ s, float* __restrict__ agg)
{
  int idx = blockIdx.x*blockDim.x + threadIdx.x;
  if (idx >= EE*NH) return;
  int e = idx >> 2, h = idx & 3;
  int src = ei[e], dst = ei[EE + e];
  float m = fdec(mkey[dst*NH + h]);
  float w = __expf(score[idx] - m);
  atomicAdd(&s[dst*NH + h], w);
  const float* vp = v + src*H48 + h*HIDD;
  float* ap = agg + (dst*NH + h)*HIDD;
  #pragma unroll
  for (int d=0; d<HIDD; d++) atomicAdd(&ap[d], w*vp[d]);
}

// ---- layer-1 finalize: head-mean + skip + relu -> h ----
__global__ void k_fin1(const float* __restrict__ agg, const float* __restrict__ s,
                       const float* __restrict__ skip, float* __restrict__ hout)
{
  int idx = blockIdx.x*blockDim.x + threadIdx.x;
  if (idx >= NN*HIDD) return;
  int node = idx / HIDD, d = idx - node*HIDD;
  float acc = 0.f;
  #pragma unroll
  for (int h=0; h<NH; h++)
    acc += agg[(node*NH+h)*HIDD + d] / (s[node*NH+h] + 1e-16f);
  acc = acc*0.25f + skip[idx];
  hout[idx] = fmaxf(acc, 0.f);
}

// ---- layer-2 finalize + node logits + A/B factors for the pair MLP ----
__global__ void k_fin2(const float* __restrict__ agg, const float* __restrict__ s,
    const float* __restrict__ skip,
    const float* __restrict__ Wn, const float* __restrict__ bn,
    const float* __restrict__ We1, const float* __restrict__ be1,
    float* __restrict__ A, float* __restrict__ B, float* __restrict__ outNL)
{
  int node = blockIdx.x*blockDim.x + threadIdx.x;
  if (node >= NN) return;
  float h[HIDD];
  #pragma unroll
  for (int d=0; d<HIDD; d++){
    float acc = 0.f;
    #pragma unroll
    for (int hh=0; hh<NH; hh++)
      acc += agg[(node*NH+hh)*HIDD + d] / (s[node*NH+hh] + 1e-16f);
    h[d] = fmaxf(acc*0.25f + skip[node*HIDD+d], 0.f);
  }
  #pragma unroll
  for (int c=0;c<NCLSS;c++){
    float acc = bn[c];
    #pragma unroll
    for (int d=0;d<HIDD;d++) acc = fmaf(h[d], Wn[d*NCLSS+c], acc);
    outNL[node*NCLSS+c] = acc;
  }
  #pragma unroll
  for (int kk=0;kk<HIDD;kk++){
    float a = be1[kk];
    float bb = 0.f;
    #pragma unroll
    for (int d=0;d<HIDD;d++){
      a  = fmaf(h[d], We1[d*HIDD+kk], a);
      bb = fmaf(h[d], We1[(HIDD+d)*HIDD+kk], bb);
    }
    A[node*HIDD+kk] = a;
    B[node*HIDD+kk] = bb;
  }
}

// ---- dense pair MLP: out[i,j,:] = relu(A[i]+B[j]) @ We2 + be2 ----
__global__ void k_edge(const float* __restrict__ A, const float* __restrict__ B,
    const float* __restrict__ We2, const float* __restrict__ be2,
    float2* __restrict__ out)
{
  int j = blockIdx.x*64 + (threadIdx.x & 63);
  int i = blockIdx.y*4  + (threadIdx.x >> 6);
  float w0[HIDD], w1[HIDD];
  #pragma unroll
  for (int kk=0;kk<HIDD;kk++){ w0[kk]=We2[kk*2]; w1[kk]=We2[kk*2+1]; }
  float c0 = be2[0], c1 = be2[1];
  const float* Ai = A + i*HIDD;
  const float* Bj = B + j*HIDD;
  #pragma unroll
  for (int kk=0;kk<HIDD;kk++){
    float t = fmaxf(Ai[kk] + Bj[kk], 0.f);
    c0 = fmaf(t, w0[kk], c0);
    c1 = fmaf(t, w1[kk], c1);
  }
  float2 pr;
  pr.x = c0;
  pr.y = c1;
  out[(size_t)i*NN + j] = pr;
}

extern "C" void kernel_launch(void* const* d_in, const int* in_sizes, int n_in,
                              void* d_out, int out_size, void* d_ws, size_t ws_size,
                              hipStream_t stream)
{
  const float* x  = (const float*)d_in[0];
  const int*  ei  = (const int*)d_in[1];
  const int*  t   = (const int*)d_in[3];
  const float* tW = (const float*)d_in[4];  const float* tb = (const float*)d_in[5];
  const float *Wq1=(const float*)d_in[6],  *bq1=(const float*)d_in[7];
  const float *Wk1=(const float*)d_in[8],  *bk1=(const float*)d_in[9];
  const float *Wv1=(const float*)d_in[10], *bv1=(const float*)d_in[11];
  const float *Ws1=(const float*)d_in[12], *bs1=(const float*)d_in[13];
  const float *Wq2=(const float*)d_in[14], *bq2=(const float*)d_in[15];
  const float *Wk2=(const float*)d_in[16], *bk2=(const float*)d_in[17];
  const float *Wv2=(const float*)d_in[18], *bv2=(const float*)d_in[19];
  const float *Ws2=(const float*)d_in[20], *bs2=(const float*)d_in[21];
  const float *Wn =(const float*)d_in[22], *bn =(const float*)d_in[23];
  const float *We1=(const float*)d_in[24], *be1=(const float*)d_in[25];
  const float *We2=(const float*)d_in[26], *be2=(const float*)d_in[27];

  float* ws   = (float*)d_ws;
  float* te   = ws;                       // 16
  float* q    = te + 16;                  // 98304
  float* k    = q + NN*H48;               // 98304
  float* v    = k + NN*H48;               // 98304
  float* skip = v + NN*H48;               // 24576
  unsigned* mkey = (unsigned*)(skip + NN*HIDD);  // 8192
  float* s    = (float*)mkey + NN*NH;     // 8192
  float* agg  = s + NN*NH;                // 98304
  float* score= agg + NN*NH*HIDD;         // 262144
  float* h    = score + EE*NH;            // 24576
  float* A    = h + NN*HIDD;              // 24576
  float* B    = A + NN*HIDD;              // 24576

  float* out_nl = (float*)d_out;
  float2* out_el = (float2*)((float*)d_out + NN*NCLSS);

  k_te<<<1, 64, 0, stream>>>(t, tW, tb, te);

  // layer 1
  k_init<<<384, 256, 0, stream>>>(mkey, s, agg);
  k_qkv1<<<384, 256, 0, stream>>>(x, te, Wq1,bq1, Wk1,bk1, Wv1,bv1, Ws1,bs1, q,k,v,skip);
  k_score<<<1024, 256, 0, stream>>>(ei, q, k, score, mkey);
  k_agg<<<1024, 256, 0, stream>>>(ei, score, mkey, v, s, agg);
  k_fin1<<<96, 256, 0, stream>>>(agg, s, skip, h);

  // layer 2
  k_init<<<384, 256, 0, stream>>>(mkey, s, agg);
  k_qkv2<<<384, 256, 0, stream>>>(h, Wq2,bq2, Wk2,bk2, Wv2,bv2, Ws2,bs2, q,k,v,skip);
  k_score<<<1024, 256, 0, stream>>>(ei, q, k, score, mkey);
  k_agg<<<1024, 256, 0, stream>>>(ei, score, mkey, v, s, agg);
  k_fin2<<<8, 256, 0, stream>>>(agg, s, skip, Wn,bn, We1,be1, A, B, out_nl);

  // dense pair MLP
  k_edge<<<dim3(32, 512), 256, 0, stream>>>(A, B, We2, be2, out_el);
}

// Round 3
// 112.504 us; speedup vs baseline: 3.0517x; 3.0517x over previous
//
#include <hip/hip_runtime.h>

#define NN 2048
#define EE 65536
#define HIDD 12
#define NH 4
#define TEDD 16
#define NCLSS 4
#define H48 48

__device__ __forceinline__ float read_t(const int* p){
  int i = *p;
  if (i >= 0 && i < 100000) return (float)i;   // int-encoded scalar (expected)
  return __int_as_float(i);                     // defensive: float-encoded scalar
}

// ---- time embedding: te[16] = sin_embed(t/100) @ time_W + time_b ----
__global__ void k_te(const int* __restrict__ t, const float* __restrict__ W,
                     const float* __restrict__ b, float* __restrict__ te)
{
  __shared__ float emb[TEDD];
  int tid = threadIdx.x;
  float tf = read_t(t) / 100.0f;
  if (tid < 8){
    float scale = __logf(10000.0f) / 7.0f;
    float v = tf * __expf(-(float)tid * scale);
    emb[tid]   = __sinf(v);
    emb[tid+8] = __cosf(v);
  }
  __syncthreads();
  if (tid < TEDD){
    float acc = b[tid];
    #pragma unroll
    for (int k=0;k<TEDD;k++) acc = fmaf(emb[k], W[k*TEDD+tid], acc);
    te[tid] = acc;
  }
}

// ---- CSR build: degree count ----
__global__ void k_deg(const int* __restrict__ ei, int* __restrict__ deg)
{
  int e = blockIdx.x*blockDim.x + threadIdx.x;
  if (e < EE) atomicAdd(&deg[ei[EE + e]], 1);
}

// ---- CSR build: exclusive scan of 2048 degrees (single block, 256 thr × 8) ----
__global__ void k_scan(const int* __restrict__ deg, int* __restrict__ off,
                       int* __restrict__ cursor)
{
  __shared__ int part[256];
  int tid = threadIdx.x;
  int loc[8]; int sum = 0;
  #pragma unroll
  for (int j=0;j<8;j++){ loc[j] = deg[tid*8+j]; sum += loc[j]; }
  part[tid] = sum;
  __syncthreads();
  for (int st=1; st<256; st<<=1){
    int v = (tid >= st) ? part[tid-st] : 0;
    __syncthreads();
    part[tid] += v;
    __syncthreads();
  }
  int pre = (tid > 0) ? part[tid-1] : 0;
  #pragma unroll
  for (int j=0;j<8;j++){
    off[tid*8+j] = pre;
    cursor[tid*8+j] = pre;
    pre += loc[j];
  }
}

// ---- CSR build: scatter src ids into per-dst edge lists ----
__global__ void k_fill(const int* __restrict__ ei, int* __restrict__ cursor,
                       int* __restrict__ csr)
{
  int e = blockIdx.x*blockDim.x + threadIdx.x;
  if (e < EE){
    int d = ei[EE + e];
    int p = atomicAdd(&cursor[d], 1);
    csr[p] = ei[e];
  }
}

// ---- layer-1 q,k,v,skip from [one-hot x | te] (20-dim input) ----
__global__ void k_qkv1(const float* __restrict__ x, const float* __restrict__ te,
    const float* __restrict__ Wq, const float* __restrict__ bq,
    const float* __restrict__ Wk, const float* __restrict__ bk,
    const float* __restrict__ Wv, const float* __restrict__ bv,
    const float* __restrict__ Ws, const float* __restrict__ bs,
    float* __restrict__ q, float* __restrict__ k, float* __restrict__ v,
    float* __restrict__ skip)
{
  int idx = blockIdx.x*blockDim.x + threadIdx.x;
  if (idx >= NN*H48) return;
  int node = idx / H48, j = idx - node*H48;
  float xin[20];
  #pragma unroll
  for (int c=0;c<NCLSS;c++) xin[c] = x[node*NCLSS+c];
  #pragma unroll
  for (int c=0;c<TEDD;c++) xin[NCLSS+c] = te[c];
  float aq=bq[j], ak=bk[j], av=bv[j];
  #pragma unroll
  for (int c=0;c<20;c++){
    float xc = xin[c];
    aq = fmaf(xc, Wq[c*H48+j], aq);
    ak = fmaf(xc, Wk[c*H48+j], ak);
    av = fmaf(xc, Wv[c*H48+j], av);
  }
  q[idx]=aq; k[idx]=ak; v[idx]=av;
  if (j < HIDD){
    float as = bs[j];
    #pragma unroll
    for (int c=0;c<20;c++) as = fmaf(xin[c], Ws[c*HIDD+j], as);
    skip[node*HIDD+j]=as;
  }
}

// ---- layer-2 q,k,v,skip from h (12-dim input) ----
__global__ void k_qkv2(const float* __restrict__ hin,
    const float* __restrict__ Wq, const float* __restrict__ bq,
    const float* __restrict__ Wk, const float* __restrict__ bk,
    const float* __restrict__ Wv, const float* __restrict__ bv,
    const float* __restrict__ Ws, const float* __restrict__ bs,
    float* __restrict__ q, float* __restrict__ k, float* __restrict__ v,
    float* __restrict__ skip)
{
  int idx = blockIdx.x*blockDim.x + threadIdx.x;
  if (idx >= NN*H48) return;
  int node = idx / H48, j = idx - node*H48;
  float xin[HIDD];
  #pragma unroll
  for (int c=0;c<HIDD;c++) xin[c] = hin[node*HIDD+c];
  float aq=bq[j], ak=bk[j], av=bv[j];
  #pragma unroll
  for (int c=0;c<HIDD;c++){
    float xc = xin[c];
    aq = fmaf(xc, Wq[c*H48+j], aq);
    ak = fmaf(xc, Wk[c*H48+j], ak);
    av = fmaf(xc, Wv[c*H48+j], av);
  }
  q[idx]=aq; k[idx]=ak; v[idx]=av;
  if (j < HIDD){
    float as = bs[j];
    #pragma unroll
    for (int c=0;c<HIDD;c++) as = fmaf(xin[c], Ws[c*HIDD+j], as);
    skip[node*HIDD+j]=as;
  }
}

// ---- gather attention: one wave per dst node; two-pass (max, then exp+acc);
//      fused head-mean + root skip + relu ----
__global__ __launch_bounds__(256) void k_attn(
    const int* __restrict__ off, const int* __restrict__ deg,
    const int* __restrict__ csr,
    const float* __restrict__ q, const float* __restrict__ k,
    const float* __restrict__ v, const float* __restrict__ skip,
    float* __restrict__ hout)
{
  int wave = threadIdx.x >> 6;
  int lane = threadIdx.x & 63;
  int node = blockIdx.x*4 + wave;
  int o  = off[node];
  int dg = deg[node];

  __shared__ float qs[4][H48];
  if (lane < H48) qs[wave][lane] = q[node*H48 + lane];
  __syncthreads();

  // pass 1: max score per head
  float m[NH] = {-INFINITY,-INFINITY,-INFINITY,-INFINITY};
  for (int base=0; base<dg; base+=64){
    int i = base + lane;
    if (i < dg){
      int src = csr[o + i];
      const float4* kp = (const float4*)(k + src*H48);
      #pragma unroll
      for (int h=0; h<NH; h++){
        float sc = 0.f;
        #pragma unroll
        for (int t4=0; t4<3; t4++){
          float4 kk = kp[h*3 + t4];
          sc = fmaf(qs[wave][h*12+t4*4+0], kk.x, sc);
          sc = fmaf(qs[wave][h*12+t4*4+1], kk.y, sc);
          sc = fmaf(qs[wave][h*12+t4*4+2], kk.z, sc);
          sc = fmaf(qs[wave][h*12+t4*4+3], kk.w, sc);
        }
        m[h] = fmaxf(m[h], sc * 0.28867513459481287f);
      }
    }
  }
  #pragma unroll
  for (int st=1; st<64; st<<=1){
    #pragma unroll
    for (int h=0; h<NH; h++) m[h] = fmaxf(m[h], __shfl_xor(m[h], st, 64));
  }

  // pass 2: exp weights, weighted-v accumulate, denominators
  float sv[NH] = {0.f,0.f,0.f,0.f};
  float acc[H48];
  #pragma unroll
  for (int d=0; d<H48; d++) acc[d] = 0.f;

  for (int base=0; base<dg; base+=64){
    int i = base + lane;
    if (i < dg){
      int src = csr[o + i];
      const float4* kp = (const float4*)(k + src*H48);
      const float4* vp = (const float4*)(v + src*H48);
      float w[NH];
      #pragma unroll
      for (int h=0; h<NH; h++){
        float sc = 0.f;
        #pragma unroll
        for (int t4=0; t4<3; t4++){
          float4 kk = kp[h*3 + t4];
          sc = fmaf(qs[wave][h*12+t4*4+0], kk.x, sc);
          sc = fmaf(qs[wave][h*12+t4*4+1], kk.y, sc);
          sc = fmaf(qs[wave][h*12+t4*4+2], kk.z, sc);
          sc = fmaf(qs[wave][h*12+t4*4+3], kk.w, sc);
        }
        w[h] = __expf(sc * 0.28867513459481287f - m[h]);
        sv[h] += w[h];
      }
      #pragma unroll
      for (int d4=0; d4<12; d4++){
        float4 vv = vp[d4];
        float wh = w[d4/3];
        acc[d4*4+0] = fmaf(wh, vv.x, acc[d4*4+0]);
        acc[d4*4+1] = fmaf(wh, vv.y, acc[d4*4+1]);
        acc[d4*4+2] = fmaf(wh, vv.z, acc[d4*4+2]);
        acc[d4*4+3] = fmaf(wh, vv.w, acc[d4*4+3]);
      }
    }
  }
  #pragma unroll
  for (int st=1; st<64; st<<=1){
    #pragma unroll
    for (int h=0; h<NH; h++) sv[h] += __shfl_xor(sv[h], st, 64);
    #pragma unroll
    for (int d=0; d<H48; d++) acc[d] += __shfl_xor(acc[d], st, 64);
  }

  if (lane < HIDD){
    float r = 0.f;
    #pragma unroll
    for (int h=0; h<NH; h++) r += acc[h*12 + lane] / (sv[h] + 1e-16f);
    r = r*0.25f + skip[node*HIDD + lane];
    hout[node*HIDD + lane] = fmaxf(r, 0.f);
  }
}

// ---- node logits + A/B factors for the pair MLP (reads h) ----
__global__ void k_fin2(const float* __restrict__ hin,
    const float* __restrict__ Wn, const float* __restrict__ bn,
    const float* __restrict__ We1, const float* __restrict__ be1,
    float* __restrict__ A, float* __restrict__ B, float* __restrict__ outNL)
{
  int node = blockIdx.x*blockDim.x + threadIdx.x;
  if (node >= NN) return;
  float h[HIDD];
  #pragma unroll
  for (int d=0; d<HIDD; d++) h[d] = hin[node*HIDD + d];
  #pragma unroll
  for (int c=0;c<NCLSS;c++){
    float acc = bn[c];
    #pragma unroll
    for (int d=0;d<HIDD;d++) acc = fmaf(h[d], Wn[d*NCLSS+c], acc);
    outNL[node*NCLSS+c] = acc;
  }
  #pragma unroll
  for (int kk=0;kk<HIDD;kk++){
    float a = be1[kk];
    float bb = 0.f;
    #pragma unroll
    for (int d=0;d<HIDD;d++){
      a  = fmaf(h[d], We1[d*HIDD+kk], a);
      bb = fmaf(h[d], We1[(HIDD+d)*HIDD+kk], bb);
    }
    A[node*HIDD+kk] = a;
    B[node*HIDD+kk] = bb;
  }
}

// ---- dense pair MLP: out[i,j,:] = relu(A[i]+B[j]) @ We2 + be2 ----
__global__ void k_edge(const float* __restrict__ A, const float* __restrict__ B,
    const float* __restrict__ We2, const float* __restrict__ be2,
    float2* __restrict__ out)
{
  int j = blockIdx.x*64 + (threadIdx.x & 63);
  int i = blockIdx.y*4  + (threadIdx.x >> 6);
  float w0[HIDD], w1[HIDD];
  #pragma unroll
  for (int kk=0;kk<HIDD;kk++){ w0[kk]=We2[kk*2]; w1[kk]=We2[kk*2+1]; }
  float c0 = be2[0], c1 = be2[1];
  const float* Ai = A + i*HIDD;
  const float* Bj = B + j*HIDD;
  #pragma unroll
  for (int kk=0;kk<HIDD;kk++){
    float t = fmaxf(Ai[kk] + Bj[kk], 0.f);
    c0 = fmaf(t, w0[kk], c0);
    c1 = fmaf(t, w1[kk], c1);
  }
  float2 pr;
  pr.x = c0;
  pr.y = c1;
  out[(size_t)i*NN + j] = pr;
}

extern "C" void kernel_launch(void* const* d_in, const int* in_sizes, int n_in,
                              void* d_out, int out_size, void* d_ws, size_t ws_size,
                              hipStream_t stream)
{
  const float* x  = (const float*)d_in[0];
  const int*  ei  = (const int*)d_in[1];
  const int*  t   = (const int*)d_in[3];
  const float* tW = (const float*)d_in[4];  const float* tb = (const float*)d_in[5];
  const float *Wq1=(const float*)d_in[6],  *bq1=(const float*)d_in[7];
  const float *Wk1=(const float*)d_in[8],  *bk1=(const float*)d_in[9];
  const float *Wv1=(const float*)d_in[10], *bv1=(const float*)d_in[11];
  const float *Ws1=(const float*)d_in[12], *bs1=(const float*)d_in[13];
  const float *Wq2=(const float*)d_in[14], *bq2=(const float*)d_in[15];
  const float *Wk2=(const float*)d_in[16], *bk2=(const float*)d_in[17];
  const float *Wv2=(const float*)d_in[18], *bv2=(const float*)d_in[19];
  const float *Ws2=(const float*)d_in[20], *bs2=(const float*)d_in[21];
  const float *Wn =(const float*)d_in[22], *bn =(const float*)d_in[23];
  const float *We1=(const float*)d_in[24], *be1=(const float*)d_in[25];
  const float *We2=(const float*)d_in[26], *be2=(const float*)d_in[27];

  float* ws   = (float*)d_ws;
  float* te   = ws;                       // 16
  float* q    = te + 16;                  // 98304
  float* k    = q + NN*H48;               // 98304
  float* v    = k + NN*H48;               // 98304
  float* skip = v + NN*H48;               // 24576
  float* h    = skip + NN*HIDD;           // 24576
  float* A    = h + NN*HIDD;              // 24576
  float* B    = A + NN*HIDD;              // 24576
  int* deg    = (int*)(B + NN*HIDD);      // 2048
  int* off    = deg + NN;                 // 2048
  int* cursor = off + NN;                 // 2048
  int* csr    = cursor + NN;              // 65536

  float* out_nl = (float*)d_out;
  float2* out_el = (float2*)((float*)d_out + NN*NCLSS);

  k_te<<<1, 64, 0, stream>>>(t, tW, tb, te);

  // CSR over dst (shared by both layers)
  hipMemsetAsync(deg, 0, NN*sizeof(int), stream);
  k_deg<<<EE/256, 256, 0, stream>>>(ei, deg);
  k_scan<<<1, 256, 0, stream>>>(deg, off, cursor);
  k_fill<<<EE/256, 256, 0, stream>>>(ei, cursor, csr);

  // layer 1
  k_qkv1<<<384, 256, 0, stream>>>(x, te, Wq1,bq1, Wk1,bk1, Wv1,bv1, Ws1,bs1, q,k,v,skip);
  k_attn<<<NN/4, 256, 0, stream>>>(off, deg, csr, q, k, v, skip, h);

  // layer 2
  k_qkv2<<<384, 256, 0, stream>>>(h, Wq2,bq2, Wk2,bk2, Wv2,bv2, Ws2,bs2, q,k,v,skip);
  k_attn<<<NN/4, 256, 0, stream>>>(off, deg, csr, q, k, v, skip, h);
  k_fin2<<<8, 256, 0, stream>>>(h, Wn,bn, We1,be1, A, B, out_nl);

  // dense pair MLP
  k_edge<<<dim3(32, 512), 256, 0, stream>>>(A, B, We2, be2, out_el);
}

// Round 4
// 88.018 us; speedup vs baseline: 3.9007x; 1.2782x over previous
//
#include <hip/hip_runtime.h>

#define NN 2048
#define EE 65536
#define HIDD 12
#define NH 4
#define TEDD 16
#define NCLSS 4
#define H48 48

__device__ __forceinline__ float read_t(const int* p){
  int i = *p;
  if (i >= 0 && i < 100000) return (float)i;   // int-encoded scalar (expected)
  return __int_as_float(i);                     // defensive: float-encoded scalar
}

// ---- time embedding + zero deg: te[16] = sin_embed(t/100) @ time_W + time_b ----
__global__ void k_te(const int* __restrict__ t, const float* __restrict__ W,
                     const float* __restrict__ b, float* __restrict__ te,
                     int* __restrict__ deg)
{
  __shared__ float emb[TEDD];
  int tid = threadIdx.x;
  for (int i = tid; i < NN; i += 64) deg[i] = 0;
  float tf = read_t(t) / 100.0f;
  if (tid < 8){
    float scale = __logf(10000.0f) / 7.0f;
    float v = tf * __expf(-(float)tid * scale);
    emb[tid]   = __sinf(v);
    emb[tid+8] = __cosf(v);
  }
  __syncthreads();
  if (tid < TEDD){
    float acc = b[tid];
    #pragma unroll
    for (int k=0;k<TEDD;k++) acc = fmaf(emb[k], W[k*TEDD+tid], acc);
    te[tid] = acc;
  }
}

// ---- CSR build: exclusive scan of 2048 degrees (single block, 256 thr × 8) ----
__global__ void k_scan(const int* __restrict__ deg, int* __restrict__ off,
                       int* __restrict__ cursor)
{
  __shared__ int part[256];
  int tid = threadIdx.x;
  int loc[8]; int sum = 0;
  #pragma unroll
  for (int j=0;j<8;j++){ loc[j] = deg[tid*8+j]; sum += loc[j]; }
  part[tid] = sum;
  __syncthreads();
  for (int st=1; st<256; st<<=1){
    int v = (tid >= st) ? part[tid-st] : 0;
    __syncthreads();
    part[tid] += v;
    __syncthreads();
  }
  int pre = (tid > 0) ? part[tid-1] : 0;
  #pragma unroll
  for (int j=0;j<8;j++){
    off[tid*8+j] = pre;
    cursor[tid*8+j] = pre;
    pre += loc[j];
  }
}

// ---- CSR build: scatter src ids into per-dst edge lists ----
__global__ void k_fill(const int* __restrict__ ei, int* __restrict__ cursor,
                       int* __restrict__ csr)
{
  int e = blockIdx.x*blockDim.x + threadIdx.x;
  if (e < EE){
    int d = ei[EE + e];
    int p = atomicAdd(&cursor[d], 1);
    csr[p] = ei[e];
  }
}

// ---- layer-1 q,k,v,skip from [one-hot x | te] (20-dim input); also deg count ----
__global__ void k_qkv1(const float* __restrict__ x, const float* __restrict__ te,
    const float* __restrict__ Wq, const float* __restrict__ bq,
    const float* __restrict__ Wk, const float* __restrict__ bk,
    const float* __restrict__ Wv, const float* __restrict__ bv,
    const float* __restrict__ Ws, const float* __restrict__ bs,
    float* __restrict__ q, float* __restrict__ k, float* __restrict__ v,
    float* __restrict__ skip,
    const int* __restrict__ ei, int* __restrict__ deg)
{
  int idx = blockIdx.x*blockDim.x + threadIdx.x;
  if (idx < EE) atomicAdd(&deg[ei[EE + idx]], 1);
  if (idx >= NN*H48) return;
  int node = idx / H48, j = idx - node*H48;
  float xin[20];
  #pragma unroll
  for (int c=0;c<NCLSS;c++) xin[c] = x[node*NCLSS+c];
  #pragma unroll
  for (int c=0;c<TEDD;c++) xin[NCLSS+c] = te[c];
  float aq=bq[j], ak=bk[j], av=bv[j];
  #pragma unroll
  for (int c=0;c<20;c++){
    float xc = xin[c];
    aq = fmaf(xc, Wq[c*H48+j], aq);
    ak = fmaf(xc, Wk[c*H48+j], ak);
    av = fmaf(xc, Wv[c*H48+j], av);
  }
  q[idx]=aq; k[idx]=ak; v[idx]=av;
  if (j < HIDD){
    float as = bs[j];
    #pragma unroll
    for (int c=0;c<20;c++) as = fmaf(xin[c], Ws[c*HIDD+j], as);
    skip[node*HIDD+j]=as;
  }
}

// ---- layer-2 q,k,v,skip from h (12-dim input) ----
__global__ void k_qkv2(const float* __restrict__ hin,
    const float* __restrict__ Wq, const float* __restrict__ bq,
    const float* __restrict__ Wk, const float* __restrict__ bk,
    const float* __restrict__ Wv, const float* __restrict__ bv,
    const float* __restrict__ Ws, const float* __restrict__ bs,
    float* __restrict__ q, float* __restrict__ k, float* __restrict__ v,
    float* __restrict__ skip)
{
  int idx = blockIdx.x*blockDim.x + threadIdx.x;
  if (idx >= NN*H48) return;
  int node = idx / H48, j = idx - node*H48;
  float xin[HIDD];
  #pragma unroll
  for (int c=0;c<HIDD;c++) xin[c] = hin[node*HIDD+c];
  float aq=bq[j], ak=bk[j], av=bv[j];
  #pragma unroll
  for (int c=0;c<HIDD;c++){
    float xc = xin[c];
    aq = fmaf(xc, Wq[c*H48+j], aq);
    ak = fmaf(xc, Wk[c*H48+j], ak);
    av = fmaf(xc, Wv[c*H48+j], av);
  }
  q[idx]=aq; k[idx]=ak; v[idx]=av;
  if (j < HIDD){
    float as = bs[j];
    #pragma unroll
    for (int c=0;c<HIDD;c++) as = fmaf(xin[c], Ws[c*HIDD+j], as);
    skip[node*HIDD+j]=as;
  }
}

// ---- gather attention: one wave per dst node; two-pass (max, then exp+acc);
//      fused head-mean + root skip + relu.
//      MODE 0: write h.  MODE 1: write node logits + A/B pair-MLP factors. ----
template<int MODE>
__global__ __launch_bounds__(256) void k_attn(
    const int* __restrict__ off, const int* __restrict__ deg,
    const int* __restrict__ csr,
    const float* __restrict__ q, const float* __restrict__ k,
    const float* __restrict__ v, const float* __restrict__ skip,
    float* __restrict__ hout,
    const float* __restrict__ Wn, const float* __restrict__ bn,
    const float* __restrict__ We1, const float* __restrict__ be1,
    float* __restrict__ A, float* __restrict__ B, float* __restrict__ outNL)
{
  int wave = threadIdx.x >> 6;
  int lane = threadIdx.x & 63;
  int node = blockIdx.x*4 + wave;
  int o  = off[node];
  int dg = deg[node];

  __shared__ float qs[4][H48];
  __shared__ float hs[4][HIDD];
  if (lane < H48) qs[wave][lane] = q[node*H48 + lane];
  __syncthreads();

  // pass 1: max score per head
  float m[NH] = {-INFINITY,-INFINITY,-INFINITY,-INFINITY};
  for (int base=0; base<dg; base+=64){
    int i = base + lane;
    if (i < dg){
      int src = csr[o + i];
      const float4* kp = (const float4*)(k + src*H48);
      #pragma unroll
      for (int h=0; h<NH; h++){
        float sc = 0.f;
        #pragma unroll
        for (int t4=0; t4<3; t4++){
          float4 kk = kp[h*3 + t4];
          sc = fmaf(qs[wave][h*12+t4*4+0], kk.x, sc);
          sc = fmaf(qs[wave][h*12+t4*4+1], kk.y, sc);
          sc = fmaf(qs[wave][h*12+t4*4+2], kk.z, sc);
          sc = fmaf(qs[wave][h*12+t4*4+3], kk.w, sc);
        }
        m[h] = fmaxf(m[h], sc * 0.28867513459481287f);
      }
    }
  }
  #pragma unroll
  for (int st=1; st<64; st<<=1){
    #pragma unroll
    for (int h=0; h<NH; h++) m[h] = fmaxf(m[h], __shfl_xor(m[h], st, 64));
  }

  // pass 2: exp weights, weighted-v accumulate, denominators
  float sv[NH] = {0.f,0.f,0.f,0.f};
  float acc[H48];
  #pragma unroll
  for (int d=0; d<H48; d++) acc[d] = 0.f;

  for (int base=0; base<dg; base+=64){
    int i = base + lane;
    if (i < dg){
      int src = csr[o + i];
      const float4* kp = (const float4*)(k + src*H48);
      const float4* vp = (const float4*)(v + src*H48);
      float w[NH];
      #pragma unroll
      for (int h=0; h<NH; h++){
        float sc = 0.f;
        #pragma unroll
        for (int t4=0; t4<3; t4++){
          float4 kk = kp[h*3 + t4];
          sc = fmaf(qs[wave][h*12+t4*4+0], kk.x, sc);
          sc = fmaf(qs[wave][h*12+t4*4+1], kk.y, sc);
          sc = fmaf(qs[wave][h*12+t4*4+2], kk.z, sc);
          sc = fmaf(qs[wave][h*12+t4*4+3], kk.w, sc);
        }
        w[h] = __expf(sc * 0.28867513459481287f - m[h]);
        sv[h] += w[h];
      }
      #pragma unroll
      for (int d4=0; d4<12; d4++){
        float4 vv = vp[d4];
        float wh = w[d4/3];
        acc[d4*4+0] = fmaf(wh, vv.x, acc[d4*4+0]);
        acc[d4*4+1] = fmaf(wh, vv.y, acc[d4*4+1]);
        acc[d4*4+2] = fmaf(wh, vv.z, acc[d4*4+2]);
        acc[d4*4+3] = fmaf(wh, vv.w, acc[d4*4+3]);
      }
    }
  }
  #pragma unroll
  for (int st=1; st<64; st<<=1){
    #pragma unroll
    for (int h=0; h<NH; h++) sv[h] += __shfl_xor(sv[h], st, 64);
    #pragma unroll
    for (int d=0; d<H48; d++) acc[d] += __shfl_xor(acc[d], st, 64);
  }

  float r = 0.f;
  if (lane < HIDD){
    #pragma unroll
    for (int h=0; h<NH; h++) r += acc[h*12 + lane] / (sv[h] + 1e-16f);
    r = r*0.25f + skip[node*HIDD + lane];
    r = fmaxf(r, 0.f);
    if (MODE == 0) hout[node*HIDD + lane] = r;
  }

  if (MODE == 1){
    if (lane < HIDD) hs[wave][lane] = r;
    __syncthreads();
    if (lane < NCLSS){                       // node logits
      float acc2 = bn[lane];
      #pragma unroll
      for (int d=0; d<HIDD; d++) acc2 = fmaf(hs[wave][d], Wn[d*NCLSS+lane], acc2);
      outNL[node*NCLSS + lane] = acc2;
    } else if (lane < 4 + HIDD){             // A factor
      int kk = lane - 4;
      float a = be1[kk];
      #pragma unroll
      for (int d=0; d<HIDD; d++) a = fmaf(hs[wave][d], We1[d*HIDD+kk], a);
      A[node*HIDD + kk] = a;
    } else if (lane < 4 + 2*HIDD){           // B factor
      int kk = lane - 4 - HIDD;
      float bb = 0.f;
      #pragma unroll
      for (int d=0; d<HIDD; d++) bb = fmaf(hs[wave][d], We1[(HIDD+d)*HIDD+kk], bb);
      B[node*HIDD + kk] = bb;
    }
  }
}

// ---- dense pair MLP: out[i,j,:] = relu(A[i]+B[j]) @ We2 + be2; 4 i-rows/thread ----
__global__ __launch_bounds__(256) void k_edge(
    const float* __restrict__ A, const float* __restrict__ B,
    const float* __restrict__ We2, const float* __restrict__ be2,
    float2* __restrict__ out)
{
  int j  = blockIdx.x*64 + (threadIdx.x & 63);
  int i0 = blockIdx.y*16 + (threadIdx.x >> 6)*4;
  float w0[HIDD], w1[HIDD], Bj[HIDD];
  #pragma unroll
  for (int kk=0;kk<HIDD;kk++){ w0[kk]=We2[kk*2]; w1[kk]=We2[kk*2+1]; }
  #pragma unroll
  for (int kk=0;kk<HIDD;kk++) Bj[kk] = B[j*HIDD + kk];
  float b0 = be2[0], b1 = be2[1];
  #pragma unroll
  for (int ii=0; ii<4; ii++){
    int i = i0 + ii;
    const float* Ai = A + i*HIDD;
    float c0 = b0, c1 = b1;
    #pragma unroll
    for (int kk=0;kk<HIDD;kk++){
      float t = fmaxf(Ai[kk] + Bj[kk], 0.f);
      c0 = fmaf(t, w0[kk], c0);
      c1 = fmaf(t, w1[kk], c1);
    }
    float2 pr; pr.x = c0; pr.y = c1;
    out[(size_t)i*NN + j] = pr;
  }
}

extern "C" void kernel_launch(void* const* d_in, const int* in_sizes, int n_in,
                              void* d_out, int out_size, void* d_ws, size_t ws_size,
                              hipStream_t stream)
{
  const float* x  = (const float*)d_in[0];
  const int*  ei  = (const int*)d_in[1];
  const int*  t   = (const int*)d_in[3];
  const float* tW = (const float*)d_in[4];  const float* tb = (const float*)d_in[5];
  const float *Wq1=(const float*)d_in[6],  *bq1=(const float*)d_in[7];
  const float *Wk1=(const float*)d_in[8],  *bk1=(const float*)d_in[9];
  const float *Wv1=(const float*)d_in[10], *bv1=(const float*)d_in[11];
  const float *Ws1=(const float*)d_in[12], *bs1=(const float*)d_in[13];
  const float *Wq2=(const float*)d_in[14], *bq2=(const float*)d_in[15];
  const float *Wk2=(const float*)d_in[16], *bk2=(const float*)d_in[17];
  const float *Wv2=(const float*)d_in[18], *bv2=(const float*)d_in[19];
  const float *Ws2=(const float*)d_in[20], *bs2=(const float*)d_in[21];
  const float *Wn =(const float*)d_in[22], *bn =(const float*)d_in[23];
  const float *We1=(const float*)d_in[24], *be1=(const float*)d_in[25];
  const float *We2=(const float*)d_in[26], *be2=(const float*)d_in[27];

  float* ws   = (float*)d_ws;
  float* te   = ws;                       // 16
  float* q    = te + 16;                  // 98304
  float* k    = q + NN*H48;               // 98304
  float* v    = k + NN*H48;               // 98304
  float* skip = v + NN*H48;               // 24576
  float* h    = skip + NN*HIDD;           // 24576
  float* A    = h + NN*HIDD;              // 24576
  float* B    = A + NN*HIDD;              // 24576
  int* deg    = (int*)(B + NN*HIDD);      // 2048
  int* off    = deg + NN;                 // 2048
  int* cursor = off + NN;                 // 2048
  int* csr    = cursor + NN;              // 65536

  float* out_nl = (float*)d_out;
  float2* out_el = (float2*)((float*)d_out + NN*NCLSS);

  // 1: time embedding + zero deg
  k_te<<<1, 64, 0, stream>>>(t, tW, tb, te, deg);
  // 2: layer-1 qkv (+ degree count)
  k_qkv1<<<384, 256, 0, stream>>>(x, te, Wq1,bq1, Wk1,bk1, Wv1,bv1, Ws1,bs1,
                                  q,k,v,skip, ei, deg);
  // 3-4: CSR offsets + fill
  k_scan<<<1, 256, 0, stream>>>(deg, off, cursor);
  k_fill<<<EE/256, 256, 0, stream>>>(ei, cursor, csr);
  // 5: layer-1 attention -> h
  k_attn<0><<<NN/4, 256, 0, stream>>>(off, deg, csr, q, k, v, skip, h,
                                      Wn,bn, We1,be1, A, B, out_nl);
  // 6: layer-2 qkv
  k_qkv2<<<384, 256, 0, stream>>>(h, Wq2,bq2, Wk2,bk2, Wv2,bv2, Ws2,bs2, q,k,v,skip);
  // 7: layer-2 attention -> node logits + A/B
  k_attn<1><<<NN/4, 256, 0, stream>>>(off, deg, csr, q, k, v, skip, h,
                                      Wn,bn, We1,be1, A, B, out_nl);
  // 8: dense pair MLP
  k_edge<<<dim3(32, 128), 256, 0, stream>>>(A, B, We2, be2, out_el);
}